// Round 1
// baseline (138.759 us; speedup 1.0000x reference)
//
#include <hip/hip_runtime.h>
#include <stdint.h>

#define TOK 256
#define IN_F 4096
#define OUT_F 4096
#define N_OUT 32

#define BN 16
#define MACRO_K 512
#define NMACRO (IN_F / MACRO_K)   // 8
#define KSTEPS (MACRO_K / 64)     // 8

typedef int v4i __attribute__((ext_vector_type(4)));

// ---------------- Kernel 1: rowwise masked quantization ----------------
__global__ __launch_bounds__(256) void oal_quant(
    const float* __restrict__ x, const int* __restrict__ oidx,
    int8_t* __restrict__ xq, float* __restrict__ xs, float* __restrict__ xo)
{
    const int row = blockIdx.x;
    const int tid = threadIdx.x;
    __shared__ unsigned char flags[IN_F];
    __shared__ float wmax[4];
    __shared__ float s_scale;

    // zero flags (16B/thread), then set outlier positions
    *reinterpret_cast<uint4*>(&flags[tid * 16]) = make_uint4(0u, 0u, 0u, 0u);
    __syncthreads();
    if (tid < N_OUT) flags[oidx[tid]] = 1;
    __syncthreads();

    const float* xr = x + (size_t)row * IN_F;
    float4 v[4];
    const float4* xp = reinterpret_cast<const float4*>(xr + tid * 16);
    #pragma unroll
    for (int i = 0; i < 4; ++i) v[i] = xp[i];

    uint4 f = *reinterpret_cast<const uint4*>(&flags[tid * 16]);
    unsigned int fw[4] = { f.x, f.y, f.z, f.w };
    float vals[16];
    #pragma unroll
    for (int i = 0; i < 4; ++i) {
        vals[i*4+0] = ((fw[i]      ) & 255u) ? 0.0f : v[i].x;
        vals[i*4+1] = ((fw[i] >>  8) & 255u) ? 0.0f : v[i].y;
        vals[i*4+2] = ((fw[i] >> 16) & 255u) ? 0.0f : v[i].z;
        vals[i*4+3] = ((fw[i] >> 24) & 255u) ? 0.0f : v[i].w;
    }

    float m = 0.0f;
    #pragma unroll
    for (int i = 0; i < 16; ++i) m = fmaxf(m, fabsf(vals[i]));
    #pragma unroll
    for (int off = 32; off > 0; off >>= 1) m = fmaxf(m, __shfl_xor(m, off, 64));
    const int lane = tid & 63, wid = tid >> 6;
    if (lane == 0) wmax[wid] = m;
    __syncthreads();
    if (tid == 0) {
        float s = fmaxf(fmaxf(wmax[0], wmax[1]), fmaxf(wmax[2], wmax[3]));
        s_scale = s;
        xs[row] = s;   // raw scale (reference dequantizes with raw scale)
    }
    __syncthreads();
    const float safe = fmaxf(s_scale, 1e-8f);

    int q[16];
    #pragma unroll
    for (int i = 0; i < 16; ++i) {
        // exact reference order: (x / safe) * 127, round-half-even, clip
        float t = vals[i] / safe * 127.0f;
        t = fminf(127.0f, fmaxf(-127.0f, rintf(t)));
        q[i] = (int)t;
    }
    uint4 packed;
    unsigned int* pw = &packed.x;
    #pragma unroll
    for (int i = 0; i < 4; ++i)
        pw[i] = (unsigned)(q[i*4] & 255) | ((unsigned)(q[i*4+1] & 255) << 8)
              | ((unsigned)(q[i*4+2] & 255) << 16) | ((unsigned)(q[i*4+3] & 255) << 24);
    *reinterpret_cast<uint4*>(xq + (size_t)row * IN_F + tid * 16) = packed;

    // gather ORIGINAL x at outlier indices
    if (tid < N_OUT) xo[row * N_OUT + tid] = xr[oidx[tid]];
}

// ---------------- Kernel 2: int8 MFMA GEMM + fused epilogue ----------------
__global__ __launch_bounds__(512, 2) void oal_gemm(
    const int8_t* __restrict__ xq, const int* __restrict__ w,
    const float* __restrict__ xs, const float* __restrict__ wscale,
    const float* __restrict__ ow, const float* __restrict__ bias,
    const float* __restrict__ xo, float* __restrict__ out)
{
    const int bn = blockIdx.x;           // N tile: output cols bn*16 .. +15
    const int tid = threadIdx.x;
    const int lane = tid & 63;
    const int wv = tid >> 6;             // wave 0..7, owns rows wv*32 .. +31

    __shared__ __align__(16) signed char Bs[2][BN][528];  // packed int8 B tile, padded stride
    __shared__ __align__(16) float XO[TOK][N_OUT];        // outlier x values

    // stage XO (8192 floats): 512 threads x 4 float4
    {
        const float4* src = reinterpret_cast<const float4*>(xo);
        float4* dst = reinterpret_cast<float4*>(&XO[0][0]);
        #pragma unroll
        for (int i = 0; i < 4; ++i) dst[tid * 4 + i] = src[tid * 4 + i];
    }

    // weight staging role: row sr (0..15), chunk sc (0..31): 16 int32 = 64B per macro
    const int sr = tid >> 5;
    const int sc = tid & 31;
    const int* wbase = w + (size_t)(bn * BN + sr) * IN_F + sc * 16;

    int4 wr_[4];
    auto load_regs = [&](int mm) {
        const int4* p = reinterpret_cast<const int4*>(wbase + mm * MACRO_K);
        #pragma unroll
        for (int i = 0; i < 4; ++i) wr_[i] = p[i];
    };
    auto pack_store = [&](int buf) {
        int p[4];
        #pragma unroll
        for (int i = 0; i < 4; ++i) {
            int4 a = wr_[i];
            p[i] = (a.x & 255) | ((a.y & 255) << 8) | ((a.z & 255) << 16) | ((a.w & 255) << 24);
        }
        *reinterpret_cast<int4*>(&Bs[buf][sr][sc * 16]) = make_int4(p[0], p[1], p[2], p[3]);
    };

    const int mrow = wv * 32;
    const int koff_lane = (lane >> 4) * 16;
    const int8_t* a0p = xq + (size_t)(mrow + (lane & 15)) * IN_F + koff_lane;
    const int8_t* a1p = a0p + 16 * IN_F;

    v4i acc0 = {0, 0, 0, 0}, acc1 = {0, 0, 0, 0};

    load_regs(0);
    pack_store(0);
    load_regs(1);             // macro-1 loads in flight during macro-0 compute
    __syncthreads();

    #pragma unroll
    for (int mm = 0; mm < NMACRO; ++mm) {
        const int cur = mm & 1;
        #pragma unroll
        for (int kk = 0; kk < KSTEPS; ++kk) {
            const int kg = mm * MACRO_K + kk * 64;
            v4i av0 = *reinterpret_cast<const v4i*>(a0p + kg);
            v4i av1 = *reinterpret_cast<const v4i*>(a1p + kg);
            v4i bv  = *reinterpret_cast<const v4i*>(&Bs[cur][lane & 15][kk * 64 + koff_lane]);
            acc0 = __builtin_amdgcn_mfma_i32_16x16x64_i8(av0, bv, acc0, 0, 0, 0);
            acc1 = __builtin_amdgcn_mfma_i32_16x16x64_i8(av1, bv, acc1, 0, 0, 0);
        }
        if (mm < NMACRO - 1) {
            pack_store(cur ^ 1);              // target buffer: readers finished before prev barrier
            if (mm < NMACRO - 2) load_regs(mm + 2);
            __syncthreads();
        }
    }

    // ---------------- epilogue ----------------
    const int ocol = bn * BN + (lane & 15);
    const float wsc = wscale[ocol] * (1.0f / 16129.0f);  // /127^2
    const float bo  = bias[ocol];
    float4 owr[8];
    const float4* owp = reinterpret_cast<const float4*>(ow + (size_t)ocol * N_OUT);
    #pragma unroll
    for (int i = 0; i < 8; ++i) owr[i] = owp[i];

    const int rbase = (lane >> 4) * 4;
    #pragma unroll
    for (int mt = 0; mt < 2; ++mt) {
        v4i a = mt ? acc1 : acc0;
        #pragma unroll
        for (int r = 0; r < 4; ++r) {
            const int t = mrow + mt * 16 + rbase + r;
            const float* xr2 = &XO[t][0];
            float dot = 0.0f;
            #pragma unroll
            for (int j = 0; j < 8; ++j) {
                float4 o4 = owr[j];
                dot += xr2[j*4+0]*o4.x + xr2[j*4+1]*o4.y + xr2[j*4+2]*o4.z + xr2[j*4+3]*o4.w;
            }
            out[(size_t)t * OUT_F + ocol] = (float)a[r] * (xs[t] * wsc) + bo + dot;
        }
    }
}

extern "C" void kernel_launch(void* const* d_in, const int* in_sizes, int n_in,
                              void* d_out, int out_size, void* d_ws, size_t ws_size,
                              hipStream_t stream) {
    const float* x      = (const float*)d_in[0];
    const int*   w      = (const int*)  d_in[1];
    const float* wscale = (const float*)d_in[2];
    const int*   oidx   = (const int*)  d_in[3];
    const float* ow     = (const float*)d_in[4];
    const float* bias   = (const float*)d_in[5];
    float* out = (float*)d_out;

    int8_t* xq = (int8_t*)d_ws;
    float*  xs = (float*)((char*)d_ws + (size_t)TOK * IN_F);
    float*  xo = (float*)((char*)d_ws + (size_t)TOK * IN_F + 1024);

    oal_quant<<<TOK, 256, 0, stream>>>(x, oidx, xq, xs, xo);
    oal_gemm<<<OUT_F / BN, 512, 0, stream>>>(xq, w, xs, wscale, ow, bias, xo, out);
}

// Round 2
// 137.177 us; speedup vs baseline: 1.0115x; 1.0115x over previous
//
#include <hip/hip_runtime.h>
#include <stdint.h>

#define TOK 256
#define IN_F 4096
#define OUT_F 4096
#define N_OUT 32

#define BN 16
#define KSTEP 64
#define NK 64          // total K steps (4096/64)
#define KPM 8          // K-steps per macro (macro = 512 of K)
#define NMACRO 8

typedef int v4i __attribute__((ext_vector_type(4)));

// ---------------- Kernel 1: rowwise masked quantization ----------------
__global__ __launch_bounds__(256) void oal_quant(
    const float* __restrict__ x, const int* __restrict__ oidx,
    int8_t* __restrict__ xq, float* __restrict__ xs, float* __restrict__ xo)
{
    const int row = blockIdx.x;
    const int tid = threadIdx.x;
    __shared__ unsigned char flags[IN_F];
    __shared__ float wmax[4];
    __shared__ float s_scale;

    // issue the row load first so it overlaps the flags setup
    const float* xr = x + (size_t)row * IN_F;
    float4 v[4];
    const float4* xp = reinterpret_cast<const float4*>(xr + tid * 16);
    #pragma unroll
    for (int i = 0; i < 4; ++i) v[i] = xp[i];

    *reinterpret_cast<uint4*>(&flags[tid * 16]) = make_uint4(0u, 0u, 0u, 0u);
    __syncthreads();
    if (tid < N_OUT) flags[oidx[tid]] = 1;
    __syncthreads();

    uint4 f = *reinterpret_cast<const uint4*>(&flags[tid * 16]);
    unsigned int fw[4] = { f.x, f.y, f.z, f.w };
    float vals[16];
    #pragma unroll
    for (int i = 0; i < 4; ++i) {
        vals[i*4+0] = ((fw[i]      ) & 255u) ? 0.0f : v[i].x;
        vals[i*4+1] = ((fw[i] >>  8) & 255u) ? 0.0f : v[i].y;
        vals[i*4+2] = ((fw[i] >> 16) & 255u) ? 0.0f : v[i].z;
        vals[i*4+3] = ((fw[i] >> 24) & 255u) ? 0.0f : v[i].w;
    }

    float m = 0.0f;
    #pragma unroll
    for (int i = 0; i < 16; ++i) m = fmaxf(m, fabsf(vals[i]));
    #pragma unroll
    for (int off = 32; off > 0; off >>= 1) m = fmaxf(m, __shfl_xor(m, off, 64));
    const int lane = tid & 63, wid = tid >> 6;
    if (lane == 0) wmax[wid] = m;
    __syncthreads();
    if (tid == 0) {
        float s = fmaxf(fmaxf(wmax[0], wmax[1]), fmaxf(wmax[2], wmax[3]));
        s_scale = s;
        xs[row] = s;   // raw scale (reference dequantizes with raw scale)
    }
    __syncthreads();
    const float safe = fmaxf(s_scale, 1e-8f);

    int q[16];
    #pragma unroll
    for (int i = 0; i < 16; ++i) {
        // exact reference order: (x / safe) * 127, round-half-even, clip
        float t = vals[i] / safe * 127.0f;
        t = fminf(127.0f, fmaxf(-127.0f, rintf(t)));
        q[i] = (int)t;
    }
    uint4 packed;
    unsigned int* pw = &packed.x;
    #pragma unroll
    for (int i = 0; i < 4; ++i)
        pw[i] = (unsigned)(q[i*4] & 255) | ((unsigned)(q[i*4+1] & 255) << 8)
              | ((unsigned)(q[i*4+2] & 255) << 16) | ((unsigned)(q[i*4+3] & 255) << 24);
    *reinterpret_cast<uint4*>(xq + (size_t)row * IN_F + tid * 16) = packed;

    if (tid < N_OUT) xo[row * N_OUT + tid] = xr[oidx[tid]];
}

// ---------------- Kernel 2: int8 MFMA GEMM + fused epilogue ----------------
// 256 blocks x 512 threads. Block bn owns output cols [bn*16, bn*16+16), all
// 256 token rows; wave wv owns rows wv*32..+31 (2 row-tiles). Weight int32 is
// loaded 2 macros deep into regs, packed to int8 into double-buffered LDS
// (shared by the 8 waves). A fragments (xq) stream through a 4-deep register
// ring so L2/L3 latency is covered ~1800 cycles ahead of consumption.
__global__ __launch_bounds__(512, 1) void oal_gemm(
    const int8_t* __restrict__ xq, const int* __restrict__ w,
    const float* __restrict__ xs, const float* __restrict__ wscale,
    const float* __restrict__ ow, const float* __restrict__ bias,
    const float* __restrict__ xo, float* __restrict__ out)
{
    const int bn = blockIdx.x;
    const int tid = threadIdx.x;
    const int lane = tid & 63;
    const int wv = tid >> 6;

    __shared__ __align__(16) signed char Bs[2][BN][528];  // packed int8 B tile
    __shared__ __align__(16) float XO[TOK][N_OUT];        // outlier x values

    // stage XO (8192 floats): 512 threads x 4 float4
    {
        const float4* src = reinterpret_cast<const float4*>(xo);
        float4* dst = reinterpret_cast<float4*>(&XO[0][0]);
        #pragma unroll
        for (int i = 0; i < 4; ++i) dst[tid * 4 + i] = src[tid * 4 + i];
    }

    // weight staging role: row sr (0..15), chunk sc (0..31): 16 int32 = 64B/macro
    const int sr = tid >> 5;
    const int sc = tid & 31;
    const int* wbase = w + (size_t)(bn * BN + sr) * IN_F + sc * 16;

    int4 wa[4], wb[4];

#define LOADW(R, mm) { const int4* p_ = reinterpret_cast<const int4*>(wbase + (mm) * (KPM * KSTEP)); \
    R[0] = p_[0]; R[1] = p_[1]; R[2] = p_[2]; R[3] = p_[3]; }

#define PACKW(R, buf) { int pk0_ = (R[0].x & 255) | ((R[0].y & 255) << 8) | ((R[0].z & 255) << 16) | ((R[0].w & 255) << 24); \
    int pk1_ = (R[1].x & 255) | ((R[1].y & 255) << 8) | ((R[1].z & 255) << 16) | ((R[1].w & 255) << 24); \
    int pk2_ = (R[2].x & 255) | ((R[2].y & 255) << 8) | ((R[2].z & 255) << 16) | ((R[2].w & 255) << 24); \
    int pk3_ = (R[3].x & 255) | ((R[3].y & 255) << 8) | ((R[3].z & 255) << 16) | ((R[3].w & 255) << 24); \
    *reinterpret_cast<int4*>(&Bs[buf][sr][sc * 16]) = make_int4(pk0_, pk1_, pk2_, pk3_); }

    const int mrow = wv * 32;
    const int koff = (lane >> 4) * 16;
    const int8_t* a0p = xq + (size_t)(mrow + (lane & 15)) * IN_F + koff;
    const int8_t* a1p = a0p + 16 * IN_F;

    v4i acc0 = {0, 0, 0, 0}, acc1 = {0, 0, 0, 0};
    v4i ar0[4], ar1[4];

    // prologue: weight macros 0,1 in flight; A ring primed with ksteps 0..3
    LOADW(wa, 0);
    LOADW(wb, 1);
    #pragma unroll
    for (int i = 0; i < 4; ++i) {
        ar0[i] = *reinterpret_cast<const v4i*>(a0p + i * KSTEP);
        ar1[i] = *reinterpret_cast<const v4i*>(a1p + i * KSTEP);
    }
    PACKW(wa, 0);        // waits only on wa's 4 loads
    LOADW(wa, 2);        // macro 2 in flight during macro 0 compute
    __syncthreads();

    #pragma unroll
    for (int mm = 0; mm < NMACRO; ++mm) {
        #pragma unroll
        for (int kk = 0; kk < KPM; ++kk) {
            const int ks = mm * KPM + kk;
            v4i bv = *reinterpret_cast<const v4i*>(&Bs[mm & 1][lane & 15][kk * KSTEP + koff]);
            acc0 = __builtin_amdgcn_mfma_i32_16x16x64_i8(ar0[ks & 3], bv, acc0, 0, 0, 0);
            acc1 = __builtin_amdgcn_mfma_i32_16x16x64_i8(ar1[ks & 3], bv, acc1, 0, 0, 0);
            if (ks + 4 < NK) {   // refill ring slot 4 ksteps ahead
                ar0[ks & 3] = *reinterpret_cast<const v4i*>(a0p + (ks + 4) * KSTEP);
                ar1[ks & 3] = *reinterpret_cast<const v4i*>(a1p + (ks + 4) * KSTEP);
            }
        }
        if (mm < NMACRO - 1) {
            // the set holding macro mm+1 is wb for even mm, wa for odd mm;
            // its loads were issued ~2 macros ago -> vmcnt wait is free.
            if ((mm & 1) == 0) {
                PACKW(wb, (mm + 1) & 1);
                if (mm + 3 < NMACRO) LOADW(wb, mm + 3);
            } else {
                PACKW(wa, (mm + 1) & 1);
                if (mm + 3 < NMACRO) LOADW(wa, mm + 3);
            }
            __syncthreads();
        }
    }

#undef LOADW
#undef PACKW

    // ---------------- epilogue ----------------
    const int ocol = bn * BN + (lane & 15);
    const float wsc = wscale[ocol] * (1.0f / 16129.0f);  // /127^2
    const float bo  = bias[ocol];
    float4 owr[8];
    const float4* owp = reinterpret_cast<const float4*>(ow + (size_t)ocol * N_OUT);
    #pragma unroll
    for (int i = 0; i < 8; ++i) owr[i] = owp[i];

    const int rbase = (lane >> 4) * 4;
    #pragma unroll
    for (int mt = 0; mt < 2; ++mt) {
        v4i a = mt ? acc1 : acc0;
        #pragma unroll
        for (int r = 0; r < 4; ++r) {
            const int t = mrow + mt * 16 + rbase + r;
            const float* xr2 = &XO[t][0];
            float dot = 0.0f;
            #pragma unroll
            for (int j = 0; j < 8; ++j) {
                float4 o4 = owr[j];
                dot += xr2[j*4+0]*o4.x + xr2[j*4+1]*o4.y + xr2[j*4+2]*o4.z + xr2[j*4+3]*o4.w;
            }
            out[(size_t)t * OUT_F + ocol] = (float)a[r] * (xs[t] * wsc) + bo + dot;
        }
    }
}

extern "C" void kernel_launch(void* const* d_in, const int* in_sizes, int n_in,
                              void* d_out, int out_size, void* d_ws, size_t ws_size,
                              hipStream_t stream) {
    const float* x      = (const float*)d_in[0];
    const int*   w      = (const int*)  d_in[1];
    const float* wscale = (const float*)d_in[2];
    const int*   oidx   = (const int*)  d_in[3];
    const float* ow     = (const float*)d_in[4];
    const float* bias   = (const float*)d_in[5];
    float* out = (float*)d_out;

    int8_t* xq = (int8_t*)d_ws;
    float*  xs = (float*)((char*)d_ws + (size_t)TOK * IN_F);
    float*  xo = (float*)((char*)d_ws + (size_t)TOK * IN_F + 1024);

    oal_quant<<<TOK, 256, 0, stream>>>(x, oidx, xq, xs, xo);
    oal_gemm<<<OUT_F / BN, 512, 0, stream>>>(xq, w, xs, wscale, ow, bias, xo, out);
}